// Round 5
// baseline (1981.018 us; speedup 1.0000x reference)
//
#include <hip/hip_runtime.h>
#include <math.h>

#define N_NODES 50000
#define N_EDGES 200000
#define N_REL   4
#define FDIM    128
#define LDSROW  132   // 128 + 4 pad for fp32 conv tiles

typedef __attribute__((ext_vector_type(8))) short short8;
typedef __attribute__((ext_vector_type(4))) float f32x4;

static __device__ __forceinline__ ushort f2bf(float f) {
  union { float f; unsigned u; } v; v.f = f;
  unsigned r = v.u + 0x7fff + ((v.u >> 16) & 1);   // RNE
  return (ushort)(r >> 16);
}
static __device__ __forceinline__ float bf2f(ushort u) {
  union { unsigned u; float f; } v; v.u = ((unsigned)u) << 16;
  return v.f;
}

// ---------- CSR build: counts ----------
__global__ void cnt_kernel(const int* __restrict__ dst, int* __restrict__ cnt) {
  int i = blockIdx.x * 256 + threadIdx.x;
  if (i < N_REL * N_EDGES) {
    int r = i / N_EDGES;
    atomicAdd(&cnt[r * N_NODES + dst[i]], 1);
  }
}

__global__ void norm_kernel(const int* __restrict__ cnt, float* __restrict__ nrm) {
  int i = blockIdx.x * 256 + threadIdx.x;
  if (i < N_REL * N_NODES) {
    int d = cnt[i];
    nrm[i] = d > 0 ? 1.f / (float)d : 0.f;
  }
}

// ---------- per-relation exclusive scan ----------
__global__ void scan_kernel(const int* __restrict__ cnt, int* __restrict__ row,
                            int* __restrict__ cursor) {
  int r = blockIdx.x;
  int t = threadIdx.x;
  const int CH = (N_NODES + 1023) / 1024;
  int s = t * CH, e2 = min(s + CH, N_NODES);
  int sum = 0;
  for (int n = s; n < e2; ++n) { row[r * N_NODES + n] = sum; sum += cnt[r * N_NODES + n]; }
  __shared__ int ts[1024];
  ts[t] = sum;
  __syncthreads();
  for (int off = 1; off < 1024; off <<= 1) {
    int v = 0;
    if (t >= off) v = ts[t - off];
    __syncthreads();
    ts[t] += v;
    __syncthreads();
  }
  int prefix = (t > 0 ? ts[t - 1] : 0) + r * N_EDGES;
  for (int n = s; n < e2; ++n) {
    int v = row[r * N_NODES + n] + prefix;
    row[r * N_NODES + n] = v;
    cursor[r * N_NODES + n] = v;
  }
}

// ---------- CSR fill: src + dst arrays ----------
__global__ void fill_kernel(const int* __restrict__ src, const int* __restrict__ dst,
                            int* __restrict__ cursor, int* __restrict__ csr_s,
                            int* __restrict__ csr_d) {
  int i = blockIdx.x * 256 + threadIdx.x;
  if (i < N_REL * N_EDGES) {
    int r = i / N_EDGES;
    int d = dst[i];
    int pos = atomicAdd(&cursor[r * N_NODES + d], 1);
    csr_s[pos] = src[i];
    csr_d[pos] = d;
  }
}

// ---------- cast x -> bf16 ----------
__global__ void cast_kernel(const float* __restrict__ x, ushort* __restrict__ xb) {
  int i = blockIdx.x * 256 + threadIdx.x;   // one float4 each
  if (i < N_NODES * FDIM / 4) {
    float4 v = ((const float4*)x)[i];
    ushort4 o;
    o.x = f2bf(v.x); o.y = f2bf(v.y); o.z = f2bf(v.z); o.w = f2bf(v.w);
    ((ushort4*)xb)[i] = o;
  }
}

// ---------- prep: P1w^T in bf16 ----------
__global__ void prep_kernel(const float* __restrict__ P1w, ushort* __restrict__ bT) {
  int i = blockIdx.x * 256 + threadIdx.x;   // 16384 total
  int c = i >> 7, k = i & 127;
  bT[i] = f2bf(P1w[k * FDIM + c]);
}

// ---------- fused conv: edge-parallel LDS-atomic gather + fp32 GEMM ----------
// hout[n] = bf16( sum_r maybe_relu( (sum_{e->n} hin[src_e]) @ W_r * nrm_r[n] + b_r ) )
__global__ void conv_fused_kernel(const ushort* __restrict__ hin,
                                  const int* __restrict__ rowp, const float* __restrict__ nrm,
                                  const int* __restrict__ csr_s, const int* __restrict__ csr_d,
                                  const float* __restrict__ W, const float* __restrict__ bias,
                                  ushort* __restrict__ hout, int do_relu) {
  __shared__ __align__(16) float et[64 * LDSROW];
  int tid  = threadIdx.x;
  int base = blockIdx.x * 64;
  int l = tid & 31;   // lane-in-group / col group
  int g = tid >> 5;   // group id (0..7)

  float tot[8][4];
#pragma unroll
  for (int e = 0; e < 8; ++e)
#pragma unroll
    for (int c = 0; c < 4; ++c) tot[e][c] = 0.f;

  for (int r = 0; r < N_REL; ++r) {
    if (r > 0) __syncthreads();   // previous GEMM readers done before zeroing
    for (int i = tid; i < (64 * LDSROW) / 4; i += 256)
      ((float4*)et)[i] = make_float4(0.f, 0.f, 0.f, 0.f);
    __syncthreads();

    // edge-parallel accumulate: tile's edges are contiguous in CSR
    int rb   = r * N_NODES;
    int tbeg = rowp[rb + base];
    int tend = (base + 64 < N_NODES) ? rowp[rb + base + 64] : (r + 1) * N_EDGES;
    for (int e = tbeg + g; e < tend; e += 8) {
      int s   = csr_s[e];
      int row = csr_d[e] - base;
      const ushort* hr = hin + (size_t)s * FDIM;
      float* er = et + row * LDSROW;
      // lane l covers elements {2l, 2l+1, 64+2l, 64+2l+1}: dword loads,
      // LDS-atomic banks are 2-way aliased (free per m136)
      ushort2 u0 = *(const ushort2*)(hr + 2 * l);
      ushort2 u1 = *(const ushort2*)(hr + 64 + 2 * l);
      atomicAdd(er + 2 * l,          bf2f(u0.x));
      atomicAdd(er + 2 * l + 1,      bf2f(u0.y));
      atomicAdd(er + 64 + 2 * l,     bf2f(u1.x));
      atomicAdd(er + 64 + 2 * l + 1, bf2f(u1.y));
    }
    __syncthreads();

    // fp32 register-blocked GEMM from LDS
    float acc[8][4];
#pragma unroll
    for (int e = 0; e < 8; ++e)
#pragma unroll
      for (int c = 0; c < 4; ++c) acc[e][c] = 0.f;

    const float* Wr    = W + (size_t)r * FDIM * FDIM;
    const float* ebase = et + g * 8 * LDSROW;
    for (int k = 0; k < FDIM; k += 4) {
      float4 w0 = ((const float4*)(Wr + (size_t)(k + 0) * FDIM))[l];
      float4 w1 = ((const float4*)(Wr + (size_t)(k + 1) * FDIM))[l];
      float4 w2 = ((const float4*)(Wr + (size_t)(k + 2) * FDIM))[l];
      float4 w3 = ((const float4*)(Wr + (size_t)(k + 3) * FDIM))[l];
#pragma unroll
      for (int e = 0; e < 8; ++e) {
        float4 ev = *(const float4*)(ebase + e * LDSROW + k);
        acc[e][0] += ev.x * w0.x + ev.y * w1.x + ev.z * w2.x + ev.w * w3.x;
        acc[e][1] += ev.x * w0.y + ev.y * w1.y + ev.z * w2.y + ev.w * w3.y;
        acc[e][2] += ev.x * w0.z + ev.y * w1.z + ev.z * w2.z + ev.w * w3.z;
        acc[e][3] += ev.x * w0.w + ev.y * w1.w + ev.z * w2.w + ev.w * w3.w;
      }
    }

    // epilogue: norm (folded), bias, relu, accumulate across relations
    float4 bv = ((const float4*)(bias + (size_t)r * FDIM))[l];
#pragma unroll
    for (int e = 0; e < 8; ++e) {
      int n = base + g * 8 + e;
      float nr = (n < N_NODES) ? nrm[rb + n] : 0.f;
      float v0 = acc[e][0] * nr + bv.x, v1 = acc[e][1] * nr + bv.y;
      float v2 = acc[e][2] * nr + bv.z, v3 = acc[e][3] * nr + bv.w;
      if (do_relu) {
        v0 = fmaxf(v0, 0.f); v1 = fmaxf(v1, 0.f);
        v2 = fmaxf(v2, 0.f); v3 = fmaxf(v3, 0.f);
      }
      tot[e][0] += v0; tot[e][1] += v1; tot[e][2] += v2; tot[e][3] += v3;
    }
  }

#pragma unroll
  for (int e = 0; e < 8; ++e) {
    int n = base + g * 8 + e;
    if (n < N_NODES) {
      ushort4 o;
      o.x = f2bf(tot[e][0]); o.y = f2bf(tot[e][1]);
      o.z = f2bf(tot[e][2]); o.w = f2bf(tot[e][3]);
      ((ushort4*)(hout + (size_t)n * FDIM))[l] = o;
    }
  }
}

// ---------- edge scoring via MFMA (bf16 h), pos+neg in one dispatch ----------
__global__ __launch_bounds__(256) void edge_mfma_kernel(
    const ushort* __restrict__ hb,
    const int* __restrict__ psrc, const int* __restrict__ pdst,
    const int* __restrict__ nsrc, const int* __restrict__ ndst,
    const ushort* __restrict__ bT, const float* __restrict__ P1b,
    const float* __restrict__ P2w, const float* __restrict__ P2b,
    float* __restrict__ out) {
  __shared__ __align__(16) short elds[64 * 128];   // bf16 E tile, XOR-swizzled
  __shared__ float partials[4][64];

  int tid  = threadIdx.x;
  int wave = tid >> 6, lane = tid & 63;
  int b = blockIdx.x;
  const int *esrc, *edst;
  float* o;
  int base;
  if (b < (N_REL * N_EDGES) / 64) {
    esrc = psrc; edst = pdst; o = out; base = b * 64;
  } else {
    esrc = nsrc; edst = ndst; o = out + (size_t)N_REL * N_EDGES;
    base = (b - (N_REL * N_EDGES) / 64) * 64;
  }

  int c0 = (2 * wave) * 16 + (lane & 15);
  int c1 = c0 + 16;
  float bz0 = P1b[c0], bz1 = P1b[c1];
  float wd0 = P2w[c0 * 2 + 1] - P2w[c0 * 2];
  float wd1 = P2w[c1 * 2 + 1] - P2w[c1 * 2];
  float cdiff = P2b[1] - P2b[0];

  short8 bfrag[2][4];
#pragma unroll
  for (int t2 = 0; t2 < 2; ++t2) {
    int c = (2 * wave + t2) * 16 + (lane & 15);
#pragma unroll
    for (int k0 = 0; k0 < 4; ++k0)
      bfrag[t2][k0] = *(const short8*)(bT + (size_t)c * 128 + k0 * 32 + (lane >> 4) * 8);
  }

  // stage E = bf16(h[s]*h[d]): 16 lanes per row (256 B bf16 rows), swizzled b128 stores
#pragma unroll
  for (int j = 0; j < 4; ++j) {
    int flat = j * 256 + tid;
    int row = flat >> 4, f8 = flat & 15;
    int ge = base + row;
    int s = esrc[ge], d = edst[ge];
    short8 a8 = *(const short8*)(hb + (size_t)s * FDIM + f8 * 8);
    short8 g8 = *(const short8*)(hb + (size_t)d * FDIM + f8 * 8);
    unsigned w[4];
#pragma unroll
    for (int i2 = 0; i2 < 4; ++i2) {
      float p0 = bf2f((ushort)a8[2 * i2])     * bf2f((ushort)g8[2 * i2]);
      float p1 = bf2f((ushort)a8[2 * i2 + 1]) * bf2f((ushort)g8[2 * i2 + 1]);
      w[i2] = (unsigned)f2bf(p0) | ((unsigned)f2bf(p1) << 16);
    }
    int byte = row * 256 + f8 * 16;
    byte ^= (row & 7) << 4;
    *(uint4*)((char*)elds + byte) = make_uint4(w[0], w[1], w[2], w[3]);
  }
  __syncthreads();

  float part[4][4];
#pragma unroll
  for (int tr = 0; tr < 4; ++tr)
#pragma unroll
    for (int j2 = 0; j2 < 4; ++j2) part[tr][j2] = 0.f;

#pragma unroll
  for (int tr = 0; tr < 4; ++tr) {
    int arow = tr * 16 + (lane & 15);
    short8 afrag[4];
#pragma unroll
    for (int k0 = 0; k0 < 4; ++k0) {
      int byte = arow * 256 + k0 * 64 + (lane >> 4) * 16;
      byte ^= (arow & 7) << 4;
      afrag[k0] = *(const short8*)((const char*)elds + byte);
    }
#pragma unroll
    for (int t2 = 0; t2 < 2; ++t2) {
      f32x4 acc = {0.f, 0.f, 0.f, 0.f};
#pragma unroll
      for (int k0 = 0; k0 < 4; ++k0)
        acc = __builtin_amdgcn_mfma_f32_16x16x32_bf16(afrag[k0], bfrag[t2][k0], acc, 0, 0, 0);
      float bz = t2 ? bz1 : bz0;
      float wdv = t2 ? wd1 : wd0;
#pragma unroll
      for (int j2 = 0; j2 < 4; ++j2)
        part[tr][j2] += fmaxf(acc[j2] + bz, 0.f) * wdv;
    }
  }

#pragma unroll
  for (int tr = 0; tr < 4; ++tr)
#pragma unroll
    for (int j2 = 0; j2 < 4; ++j2) {
      float v = part[tr][j2];
      v += __shfl_xor(v, 1);
      v += __shfl_xor(v, 2);
      v += __shfl_xor(v, 4);
      v += __shfl_xor(v, 8);
      if ((lane & 15) == 0) partials[wave][tr * 16 + (lane >> 4) * 4 + j2] = v;
    }
  __syncthreads();

  if (tid < 64) {
    float s2 = partials[0][tid] + partials[1][tid] + partials[2][tid] + partials[3][tid] + cdiff;
    o[base + tid] = 1.f / (1.f + expf(-s2));
  }
}

extern "C" void kernel_launch(void* const* d_in, const int* in_sizes, int n_in,
                              void* d_out, int out_size, void* d_ws, size_t ws_size,
                              hipStream_t stream) {
  const float* x   = (const float*)d_in[0];
  const float* W1  = (const float*)d_in[1];
  const float* b1  = (const float*)d_in[2];
  const float* W2  = (const float*)d_in[3];
  const float* b2  = (const float*)d_in[4];
  const float* P1w = (const float*)d_in[5];
  const float* P1b = (const float*)d_in[6];
  const float* P2w = (const float*)d_in[7];
  const float* P2b = (const float*)d_in[8];
  const int* src     = (const int*)d_in[9];
  const int* dst     = (const int*)d_in[10];
  const int* pos_src = (const int*)d_in[11];
  const int* pos_dst = (const int*)d_in[12];
  const int* neg_src = (const int*)d_in[13];
  const int* neg_dst = (const int*)d_in[14];
  float* out = (float*)d_out;

  char* ws = (char*)d_ws;
  int*    cnt    = (int*)ws;     ws += (size_t)N_REL * N_NODES * 4;
  int*    rowp   = (int*)ws;     ws += (size_t)N_REL * N_NODES * 4;
  int*    cursor = (int*)ws;     ws += (size_t)N_REL * N_NODES * 4;
  int*    csr_s  = (int*)ws;     ws += (size_t)N_REL * N_EDGES * 4;
  int*    csr_d  = (int*)ws;     ws += (size_t)N_REL * N_EDGES * 4;
  float*  nrm    = (float*)ws;   ws += (size_t)N_REL * N_NODES * 4;
  ushort* bT     = (ushort*)ws;  ws += (size_t)FDIM * FDIM * 2;
  ushort* xb     = (ushort*)ws;  ws += (size_t)N_NODES * FDIM * 2;
  ushort* h1b    = (ushort*)ws;  ws += (size_t)N_NODES * FDIM * 2;
  ushort* h2b    = (ushort*)ws;

  // ---- CSR build (shared by both layers) + casts/prep ----
  hipMemsetAsync(cnt, 0, (size_t)N_REL * N_NODES * 4, stream);
  cnt_kernel<<<(N_REL * N_EDGES + 255) / 256, 256, 0, stream>>>(dst, cnt);
  norm_kernel<<<(N_REL * N_NODES + 255) / 256, 256, 0, stream>>>(cnt, nrm);
  scan_kernel<<<N_REL, 1024, 0, stream>>>(cnt, rowp, cursor);
  fill_kernel<<<(N_REL * N_EDGES + 255) / 256, 256, 0, stream>>>(src, dst, cursor, csr_s, csr_d);
  cast_kernel<<<(N_NODES * FDIM / 4 + 255) / 256, 256, 0, stream>>>(x, xb);
  prep_kernel<<<(FDIM * FDIM) / 256, 256, 0, stream>>>(P1w, bT);

  // ---- layer 1 / layer 2 ----
  conv_fused_kernel<<<(N_NODES + 63) / 64, 256, 0, stream>>>(
      xb, rowp, nrm, csr_s, csr_d, W1, b1, h1b, 1);
  conv_fused_kernel<<<(N_NODES + 63) / 64, 256, 0, stream>>>(
      h1b, rowp, nrm, csr_s, csr_d, W2, b2, h2b, 0);

  // ---- edge scores: pos blocks then neg blocks in one dispatch ----
  edge_mfma_kernel<<<2 * (N_REL * N_EDGES) / 64, 256, 0, stream>>>(
      h2b, pos_src, pos_dst, neg_src, neg_dst, bT, P1b, P2w, P2b, out);
}

// Round 6
// 699.857 us; speedup vs baseline: 2.8306x; 2.8306x over previous
//
#include <hip/hip_runtime.h>
#include <math.h>

#define N_NODES 50000
#define N_EDGES 200000
#define N_REL   4
#define FDIM    128

typedef __attribute__((ext_vector_type(8))) short short8;
typedef __attribute__((ext_vector_type(4))) float f32x4;

static __device__ __forceinline__ ushort f2bf(float f) {
  union { float f; unsigned u; } v; v.f = f;
  unsigned r = v.u + 0x7fff + ((v.u >> 16) & 1);   // RNE
  return (ushort)(r >> 16);
}
static __device__ __forceinline__ float bf2f(ushort u) {
  union { unsigned u; float f; } v; v.u = ((unsigned)u) << 16;
  return v.f;
}

// ---------- CSR build: counts ----------
__global__ void cnt_kernel(const int* __restrict__ dst, int* __restrict__ cnt) {
  int i = blockIdx.x * 256 + threadIdx.x;
  if (i < N_REL * N_EDGES) {
    int r = i / N_EDGES;
    atomicAdd(&cnt[r * N_NODES + dst[i]], 1);
  }
}

__global__ void norm_kernel(const int* __restrict__ cnt, float* __restrict__ nrm) {
  int i = blockIdx.x * 256 + threadIdx.x;
  if (i < N_REL * N_NODES) {
    int d = cnt[i];
    nrm[i] = d > 0 ? 1.f / (float)d : 0.f;
  }
}

// ---------- per-relation exclusive scan ----------
__global__ void scan_kernel(const int* __restrict__ cnt, int* __restrict__ row,
                            int* __restrict__ cursor) {
  int r = blockIdx.x;
  int t = threadIdx.x;
  const int CH = (N_NODES + 1023) / 1024;
  int s = t * CH, e2 = min(s + CH, N_NODES);
  int sum = 0;
  for (int n = s; n < e2; ++n) { row[r * N_NODES + n] = sum; sum += cnt[r * N_NODES + n]; }
  __shared__ int ts[1024];
  ts[t] = sum;
  __syncthreads();
  for (int off = 1; off < 1024; off <<= 1) {
    int v = 0;
    if (t >= off) v = ts[t - off];
    __syncthreads();
    ts[t] += v;
    __syncthreads();
  }
  int prefix = (t > 0 ? ts[t - 1] : 0) + r * N_EDGES;
  for (int n = s; n < e2; ++n) {
    int v = row[r * N_NODES + n] + prefix;
    row[r * N_NODES + n] = v;
    cursor[r * N_NODES + n] = v;
  }
}

// ---------- CSR fill ----------
__global__ void fill_kernel(const int* __restrict__ src, const int* __restrict__ dst,
                            int* __restrict__ cursor, int* __restrict__ csr_s) {
  int i = blockIdx.x * 256 + threadIdx.x;
  if (i < N_REL * N_EDGES) {
    int r = i / N_EDGES;
    int pos = atomicAdd(&cursor[r * N_NODES + dst[i]], 1);
    csr_s[pos] = src[i];
  }
}

// ---------- cast x -> bf16 ----------
__global__ void cast_kernel(const float* __restrict__ x, ushort* __restrict__ xb) {
  int i = blockIdx.x * 256 + threadIdx.x;
  if (i < N_NODES * FDIM / 4) {
    float4 v = ((const float4*)x)[i];
    ushort4 o;
    o.x = f2bf(v.x); o.y = f2bf(v.y); o.z = f2bf(v.z); o.w = f2bf(v.w);
    ((ushort4*)xb)[i] = o;
  }
}

// ---------- prep: P1w^T in bf16 ----------
__global__ void prep_kernel(const float* __restrict__ P1w, ushort* __restrict__ bT) {
  int i = blockIdx.x * 256 + threadIdx.x;   // 16384
  int c = i >> 7, k = i & 127;
  bT[i] = f2bf(P1w[k * FDIM + c]);
}

// ---------- prep: W[4][k][c] -> wT[4][c][k] bf16 ----------
__global__ void prepW_kernel(const float* __restrict__ W, ushort* __restrict__ wT) {
  int i = blockIdx.x * 256 + threadIdx.x;   // 65536
  int r = i >> 14, c = (i >> 7) & 127, k = i & 127;
  wT[i] = f2bf(W[(r << 14) + (k << 7) + c]);
}

// ---------- fused conv: register gather + bf16 MFMA GEMM over 4 relations ----------
// hout[n] = bf16( sum_r maybe_relu( (sum_{e->n} hin[src_e]) @ W_r * nrm_r[n] + b_r ) )
__global__ __launch_bounds__(256) void conv_mfma_kernel(
    const ushort* __restrict__ hin, const int* __restrict__ rowp,
    const int* __restrict__ cnt, const float* __restrict__ nrm,
    const int* __restrict__ csr_s, const ushort* __restrict__ wT,
    const float* __restrict__ bias, ushort* __restrict__ hout, int do_relu) {
  __shared__ __align__(16) short elds[64 * 128];   // bf16 agg tile, XOR-swizzled
  __shared__ float nrm_lds[64];
  int tid  = threadIdx.x;
  int wave = tid >> 6, lane = tid & 63;
  int base = blockIdx.x * 64;
  int ig = tid >> 4, l16 = tid & 15;   // 16 gather groups × 16 lanes

  float tot[4][2][4];
#pragma unroll
  for (int tr = 0; tr < 4; ++tr)
#pragma unroll
    for (int t2 = 0; t2 < 2; ++t2)
#pragma unroll
      for (int j2 = 0; j2 < 4; ++j2) tot[tr][t2][j2] = 0.f;

  for (int r = 0; r < N_REL; ++r) {
    if (r > 0) __syncthreads();   // previous MFMA readers done before restaging
    if (tid < 64) {
      int n = base + tid;
      nrm_lds[tid] = (n < N_NODES) ? nrm[r * N_NODES + n] : 0.f;
    }

    // gather: group ig owns rows {ig, ig+16, ig+32, ig+48}; 16B loads, idx prefetch
    for (int rr = ig; rr < 64; rr += 16) {
      int n = base + rr;
      float a8[8];
#pragma unroll
      for (int q = 0; q < 8; ++q) a8[q] = 0.f;
      if (n < N_NODES) {
        int idx = r * N_NODES + n;
        int beg = rowp[idx], num = cnt[idx];
        int sN = (num > 0) ? csr_s[beg] : 0;
        for (int j = 0; j < num; ++j) {
          int s = sN;
          if (j + 1 < num) sN = csr_s[beg + j + 1];
          uint4 hv = *(const uint4*)(hin + (size_t)s * FDIM + l16 * 8);
          a8[0] += bf2f((ushort)(hv.x & 0xffff)); a8[1] += bf2f((ushort)(hv.x >> 16));
          a8[2] += bf2f((ushort)(hv.y & 0xffff)); a8[3] += bf2f((ushort)(hv.y >> 16));
          a8[4] += bf2f((ushort)(hv.z & 0xffff)); a8[5] += bf2f((ushort)(hv.z >> 16));
          a8[6] += bf2f((ushort)(hv.w & 0xffff)); a8[7] += bf2f((ushort)(hv.w >> 16));
        }
      }
      unsigned w0 = (unsigned)f2bf(a8[0]) | ((unsigned)f2bf(a8[1]) << 16);
      unsigned w1 = (unsigned)f2bf(a8[2]) | ((unsigned)f2bf(a8[3]) << 16);
      unsigned w2 = (unsigned)f2bf(a8[4]) | ((unsigned)f2bf(a8[5]) << 16);
      unsigned w3 = (unsigned)f2bf(a8[6]) | ((unsigned)f2bf(a8[7]) << 16);
      int byte = rr * 256 + l16 * 16;
      byte ^= (rr & 7) << 4;
      *(uint4*)((char*)elds + byte) = make_uint4(w0, w1, w2, w3);
    }
    __syncthreads();

    // B fragments: wT[r][c][k], c = wave*32 + t2*16 + (lane&15)
    short8 bfrag[2][4];
#pragma unroll
    for (int t2 = 0; t2 < 2; ++t2) {
      int c = wave * 32 + t2 * 16 + (lane & 15);
#pragma unroll
      for (int k0 = 0; k0 < 4; ++k0)
        bfrag[t2][k0] = *(const short8*)(wT + ((size_t)r * FDIM + c) * FDIM + k0 * 32 + (lane >> 4) * 8);
    }

#pragma unroll
    for (int tr = 0; tr < 4; ++tr) {
      int arow = tr * 16 + (lane & 15);
      short8 afrag[4];
#pragma unroll
      for (int k0 = 0; k0 < 4; ++k0) {
        int byte = arow * 256 + k0 * 64 + (lane >> 4) * 16;
        byte ^= (arow & 7) << 4;
        afrag[k0] = *(const short8*)((const char*)elds + byte);
      }
#pragma unroll
      for (int t2 = 0; t2 < 2; ++t2) {
        f32x4 acc = {0.f, 0.f, 0.f, 0.f};
#pragma unroll
        for (int k0 = 0; k0 < 4; ++k0)
          acc = __builtin_amdgcn_mfma_f32_16x16x32_bf16(afrag[k0], bfrag[t2][k0], acc, 0, 0, 0);
        float bv = bias[r * FDIM + wave * 32 + t2 * 16 + (lane & 15)];
#pragma unroll
        for (int j2 = 0; j2 < 4; ++j2) {
          float nr = nrm_lds[tr * 16 + (lane >> 4) * 4 + j2];
          float v = acc[j2] * nr + bv;
          if (do_relu) v = fmaxf(v, 0.f);
          tot[tr][t2][j2] += v;
        }
      }
    }
  }

  // write hout: elem (row = tr*16+(lane>>4)*4+j2, col = wave*32+t2*16+(lane&15))
#pragma unroll
  for (int tr = 0; tr < 4; ++tr)
#pragma unroll
    for (int t2 = 0; t2 < 2; ++t2)
#pragma unroll
      for (int j2 = 0; j2 < 4; ++j2) {
        int n = base + tr * 16 + (lane >> 4) * 4 + j2;
        if (n < N_NODES)
          hout[(size_t)n * FDIM + wave * 32 + t2 * 16 + (lane & 15)] = f2bf(tot[tr][t2][j2]);
      }
}

// ---------- edge scoring via MFMA (bf16 h), pos+neg in one dispatch ----------
__global__ __launch_bounds__(256) void edge_mfma_kernel(
    const ushort* __restrict__ hb,
    const int* __restrict__ psrc, const int* __restrict__ pdst,
    const int* __restrict__ nsrc, const int* __restrict__ ndst,
    const ushort* __restrict__ bT, const float* __restrict__ P1b,
    const float* __restrict__ P2w, const float* __restrict__ P2b,
    float* __restrict__ out) {
  __shared__ __align__(16) short elds[64 * 128];   // bf16 E tile, XOR-swizzled
  __shared__ float partials[4][64];

  int tid  = threadIdx.x;
  int wave = tid >> 6, lane = tid & 63;
  int b = blockIdx.x;
  const int *esrc, *edst;
  float* o;
  int base;
  if (b < (N_REL * N_EDGES) / 64) {
    esrc = psrc; edst = pdst; o = out; base = b * 64;
  } else {
    esrc = nsrc; edst = ndst; o = out + (size_t)N_REL * N_EDGES;
    base = (b - (N_REL * N_EDGES) / 64) * 64;
  }

  int c0 = (2 * wave) * 16 + (lane & 15);
  int c1 = c0 + 16;
  float bz0 = P1b[c0], bz1 = P1b[c1];
  float wd0 = P2w[c0 * 2 + 1] - P2w[c0 * 2];
  float wd1 = P2w[c1 * 2 + 1] - P2w[c1 * 2];
  float cdiff = P2b[1] - P2b[0];

  short8 bfrag[2][4];
#pragma unroll
  for (int t2 = 0; t2 < 2; ++t2) {
    int c = (2 * wave + t2) * 16 + (lane & 15);
#pragma unroll
    for (int k0 = 0; k0 < 4; ++k0)
      bfrag[t2][k0] = *(const short8*)(bT + (size_t)c * 128 + k0 * 32 + (lane >> 4) * 8);
  }

#pragma unroll
  for (int j = 0; j < 4; ++j) {
    int flat = j * 256 + tid;
    int row = flat >> 4, f8 = flat & 15;
    int ge = base + row;
    int s = esrc[ge], d = edst[ge];
    short8 a8 = *(const short8*)(hb + (size_t)s * FDIM + f8 * 8);
    short8 g8 = *(const short8*)(hb + (size_t)d * FDIM + f8 * 8);
    unsigned w[4];
#pragma unroll
    for (int i2 = 0; i2 < 4; ++i2) {
      float p0 = bf2f((ushort)a8[2 * i2])     * bf2f((ushort)g8[2 * i2]);
      float p1 = bf2f((ushort)a8[2 * i2 + 1]) * bf2f((ushort)g8[2 * i2 + 1]);
      w[i2] = (unsigned)f2bf(p0) | ((unsigned)f2bf(p1) << 16);
    }
    int byte = row * 256 + f8 * 16;
    byte ^= (row & 7) << 4;
    *(uint4*)((char*)elds + byte) = make_uint4(w[0], w[1], w[2], w[3]);
  }
  __syncthreads();

  float part[4][4];
#pragma unroll
  for (int tr = 0; tr < 4; ++tr)
#pragma unroll
    for (int j2 = 0; j2 < 4; ++j2) part[tr][j2] = 0.f;

#pragma unroll
  for (int tr = 0; tr < 4; ++tr) {
    int arow = tr * 16 + (lane & 15);
    short8 afrag[4];
#pragma unroll
    for (int k0 = 0; k0 < 4; ++k0) {
      int byte = arow * 256 + k0 * 64 + (lane >> 4) * 16;
      byte ^= (arow & 7) << 4;
      afrag[k0] = *(const short8*)((const char*)elds + byte);
    }
#pragma unroll
    for (int t2 = 0; t2 < 2; ++t2) {
      f32x4 acc = {0.f, 0.f, 0.f, 0.f};
#pragma unroll
      for (int k0 = 0; k0 < 4; ++k0)
        acc = __builtin_amdgcn_mfma_f32_16x16x32_bf16(afrag[k0], bfrag[t2][k0], acc, 0, 0, 0);
      float bz = t2 ? bz1 : bz0;
      float wdv = t2 ? wd1 : wd0;
#pragma unroll
      for (int j2 = 0; j2 < 4; ++j2)
        part[tr][j2] += fmaxf(acc[j2] + bz, 0.f) * wdv;
    }
  }

#pragma unroll
  for (int tr = 0; tr < 4; ++tr)
#pragma unroll
    for (int j2 = 0; j2 < 4; ++j2) {
      float v = part[tr][j2];
      v += __shfl_xor(v, 1);
      v += __shfl_xor(v, 2);
      v += __shfl_xor(v, 4);
      v += __shfl_xor(v, 8);
      if ((lane & 15) == 0) partials[wave][tr * 16 + (lane >> 4) * 4 + j2] = v;
    }
  __syncthreads();

  if (tid < 64) {
    float s2 = partials[0][tid] + partials[1][tid] + partials[2][tid] + partials[3][tid] + cdiff;
    o[base + tid] = 1.f / (1.f + expf(-s2));
  }
}

extern "C" void kernel_launch(void* const* d_in, const int* in_sizes, int n_in,
                              void* d_out, int out_size, void* d_ws, size_t ws_size,
                              hipStream_t stream) {
  const float* x   = (const float*)d_in[0];
  const float* W1  = (const float*)d_in[1];
  const float* b1  = (const float*)d_in[2];
  const float* W2  = (const float*)d_in[3];
  const float* b2  = (const float*)d_in[4];
  const float* P1w = (const float*)d_in[5];
  const float* P1b = (const float*)d_in[6];
  const float* P2w = (const float*)d_in[7];
  const float* P2b = (const float*)d_in[8];
  const int* src     = (const int*)d_in[9];
  const int* dst     = (const int*)d_in[10];
  const int* pos_src = (const int*)d_in[11];
  const int* pos_dst = (const int*)d_in[12];
  const int* neg_src = (const int*)d_in[13];
  const int* neg_dst = (const int*)d_in[14];
  float* out = (float*)d_out;

  char* ws = (char*)d_ws;
  int*    cnt    = (int*)ws;     ws += (size_t)N_REL * N_NODES * 4;
  int*    rowp   = (int*)ws;     ws += (size_t)N_REL * N_NODES * 4;
  int*    cursor = (int*)ws;     ws += (size_t)N_REL * N_NODES * 4;
  int*    csr_s  = (int*)ws;     ws += (size_t)N_REL * N_EDGES * 4;
  float*  nrm    = (float*)ws;   ws += (size_t)N_REL * N_NODES * 4;
  ushort* bT     = (ushort*)ws;  ws += (size_t)FDIM * FDIM * 2;
  ushort* wT1    = (ushort*)ws;  ws += (size_t)N_REL * FDIM * FDIM * 2;
  ushort* wT2    = (ushort*)ws;  ws += (size_t)N_REL * FDIM * FDIM * 2;
  ushort* xb     = (ushort*)ws;  ws += (size_t)N_NODES * FDIM * 2;
  ushort* h1b    = (ushort*)ws;  ws += (size_t)N_NODES * FDIM * 2;
  ushort* h2b    = (ushort*)ws;

  // ---- CSR build (shared by both layers) + casts/prep ----
  hipMemsetAsync(cnt, 0, (size_t)N_REL * N_NODES * 4, stream);
  cnt_kernel<<<(N_REL * N_EDGES + 255) / 256, 256, 0, stream>>>(dst, cnt);
  norm_kernel<<<(N_REL * N_NODES + 255) / 256, 256, 0, stream>>>(cnt, nrm);
  scan_kernel<<<N_REL, 1024, 0, stream>>>(cnt, rowp, cursor);
  fill_kernel<<<(N_REL * N_EDGES + 255) / 256, 256, 0, stream>>>(src, dst, cursor, csr_s);
  cast_kernel<<<(N_NODES * FDIM / 4 + 255) / 256, 256, 0, stream>>>(x, xb);
  prep_kernel<<<(FDIM * FDIM) / 256, 256, 0, stream>>>(P1w, bT);
  prepW_kernel<<<(N_REL * FDIM * FDIM) / 256, 256, 0, stream>>>(W1, wT1);
  prepW_kernel<<<(N_REL * FDIM * FDIM) / 256, 256, 0, stream>>>(W2, wT2);

  // ---- layer 1 / layer 2 ----
  conv_mfma_kernel<<<(N_NODES + 63) / 64, 256, 0, stream>>>(
      xb, rowp, cnt, nrm, csr_s, wT1, b1, h1b, 1);
  conv_mfma_kernel<<<(N_NODES + 63) / 64, 256, 0, stream>>>(
      h1b, rowp, cnt, nrm, csr_s, wT2, b2, h2b, 0);

  // ---- edge scores: pos blocks then neg blocks in one dispatch ----
  edge_mfma_kernel<<<2 * (N_REL * N_EDGES) / 64, 256, 0, stream>>>(
      h2b, pos_src, pos_dst, neg_src, neg_dst, bT, P1b, P2w, P2b, out);
}